// Round 9
// baseline (108.034 us; speedup 1.0000x reference)
//
#include <hip/hip_runtime.h>
#include <hip/hip_bf16.h>
#include <math.h>

#define D_MODEL 256
#define EXPERT_DIM 512
#define NUM_EXPERTS 8
#define T_TOKENS 4096
#define TM 64
#define NGB 256      // gate blocks (16 tokens each)
#define XS_LD 264    // 256+8 bf16 pad: 528B row (measured 0 conflicts)

typedef unsigned short ushort_t;
typedef short short8_t __attribute__((ext_vector_type(8)));
typedef float f32x4 __attribute__((ext_vector_type(4)));

__device__ __forceinline__ ushort_t f2bf(float f) {
    unsigned int u = __float_as_uint(f);
    u += 0x7FFFu + ((u >> 16) & 1u);   // round-to-nearest-even
    return (ushort_t)(u >> 16);
}
__device__ __forceinline__ float bf2f(ushort_t u) {
    return __uint_as_float((unsigned int)u << 16);
}

// ---------------------------------------------------------------------------
// Fused prep (identical to r8).
// Blocks 0..255: gate, 16 tokens/block, 16 threads/token, register x,
//   16-lane shuffle reduce, LDS-atomic compaction into per-(seg,expert)
//   width-16 segments; plain-store counts; emits bf16 xb.
// Blocks 256..1279: weight convert fp32 -> bf16 MFMA-fragment order.
// W1f: idx = e<<14 | ntile(5b)<<9 | ks(3b)<<6 | lane   (8 bf16 elems each)
// W2f: idx = e<<14 | half<<13 | ntile(4b)<<9 | ks(3b)<<6 | lane
// ---------------------------------------------------------------------------
__global__ __launch_bounds__(256) void prep_kernel(
    const float* __restrict__ x, const float* __restrict__ Wg,
    const float* __restrict__ bg, const float* __restrict__ bias,
    const float* __restrict__ W1, const float* __restrict__ W2,
    ushort_t* __restrict__ W1f, ushort_t* __restrict__ W2f,
    ushort_t* __restrict__ xb,
    int* __restrict__ gcounts, int* __restrict__ lists,
    float* __restrict__ wts, int* __restrict__ slots)
{
    __shared__ int lcount[NUM_EXPERTS];
    const int tid = threadIdx.x;

    if (blockIdx.x < NGB) {
        // ---------------- gate role ----------------
        const int gb = blockIdx.x;
        const int r = tid >> 4;        // token 0..15
        const int c = tid & 15;        // k-chunk 0..15 (16 k each)
        const int t = gb * 16 + r;
        if (tid < NUM_EXPERTS) lcount[tid] = 0;

        float xr[16];
        const float4* xp = (const float4*)(x + (size_t)t * D_MODEL + c * 16);
#pragma unroll
        for (int q = 0; q < 4; ++q) {
            float4 v = xp[q];
            xr[q * 4 + 0] = v.x; xr[q * 4 + 1] = v.y;
            xr[q * 4 + 2] = v.z; xr[q * 4 + 3] = v.w;
        }
        ushort_t o16[16];
#pragma unroll
        for (int j = 0; j < 16; ++j) o16[j] = f2bf(xr[j]);
        ushort_t* xbp = xb + (size_t)t * D_MODEL + c * 16;
        *(int4*)(xbp)     = *(int4*)(o16);
        *(int4*)(xbp + 8) = *(int4*)(o16 + 8);

        float acc[NUM_EXPERTS];
#pragma unroll
        for (int e = 0; e < NUM_EXPERTS; ++e) acc[e] = 0.f;
#pragma unroll
        for (int j = 0; j < 16; ++j) {
            const float4* wg = (const float4*)(Wg + (c * 16 + j) * NUM_EXPERTS);
            float4 w0 = wg[0], w1 = wg[1];
            float xv = xr[j];
            acc[0] += xv * w0.x; acc[1] += xv * w0.y;
            acc[2] += xv * w0.z; acc[3] += xv * w0.w;
            acc[4] += xv * w1.x; acc[5] += xv * w1.y;
            acc[6] += xv * w1.z; acc[7] += xv * w1.w;
        }
#pragma unroll
        for (int e = 0; e < NUM_EXPERTS; ++e) {
#pragma unroll
            for (int s = 1; s < 16; s <<= 1) acc[e] += __shfl_xor(acc[e], s);
        }
        __syncthreads();
        if (c == 0) {
            float v0 = -3.0e38f, v1 = -3.0e38f; int i0 = 0, i1 = 0;
#pragma unroll
            for (int e = 0; e < NUM_EXPERTS; ++e) {
                float v = acc[e] + bg[e] + bias[e];
                if (v > v0) { v1 = v0; i1 = i0; v0 = v; i0 = e; }
                else if (v > v1) { v1 = v; i1 = e; }
            }
            float e1 = __expf(v1 - v0);
            float inv = 1.f / (1.f + e1);
            float w0 = inv, w1 = e1 * inv;

            int p0 = atomicAdd(&lcount[i0], 1);    // LDS atomics only
            int p1 = atomicAdd(&lcount[i1], 1);
            lists[i0 * T_TOKENS + gb * 16 + p0] = t;
            wts  [i0 * T_TOKENS + gb * 16 + p0] = w0;
            lists[i1 * T_TOKENS + gb * 16 + p1] = t;
            wts  [i1 * T_TOKENS + gb * 16 + p1] = w1;
            slots[t] = (i0 << 12 | gb << 4 | p0) | ((i1 << 12 | gb << 4 | p1) << 16);
        }
        __syncthreads();
        if (tid < NUM_EXPERTS) gcounts[gb * NUM_EXPERTS + tid] = lcount[tid];
    } else {
        // ---------------- convert role ----------------
        int gid = (blockIdx.x - NGB) * 256 + tid;    // 0 .. 262143
        bool isW2 = gid >= 131072;
        int idx = isW2 ? gid - 131072 : gid;
        int lane = idx & 63;
        int l15 = lane & 15, quad = lane >> 4;
        int ks = (idx >> 6) & 7;
        ushort_t o[8];
        if (!isW2) {
            int ntile = (idx >> 9) & 31, e = idx >> 14;
            int nn = ntile * 16 + l15;
            int k0 = ks * 32 + quad * 8;
            const float* s = W1 + ((size_t)e * D_MODEL + k0) * EXPERT_DIM + nn;
#pragma unroll
            for (int j = 0; j < 8; ++j) o[j] = f2bf(s[j * EXPERT_DIM]);
            *(int4*)(W1f + (size_t)idx * 8) = *(int4*)o;
        } else {
            int ntile = (idx >> 9) & 15, half = (idx >> 13) & 1, e = idx >> 14;
            int nn = ntile * 16 + l15;
            int k0 = half * 256 + ks * 32 + quad * 8;
            const float* s = W2 + ((size_t)e * EXPERT_DIM + k0) * D_MODEL + nn;
#pragma unroll
            for (int j = 0; j < 8; ++j) o[j] = f2bf(s[j * D_MODEL]);
            *(int4*)(W2f + (size_t)idx * 8) = *(int4*)o;
        }
    }
}

// ---------------------------------------------------------------------------
// Expert FFN, bf16 MFMA. grid (expert, half, tile64), block 256 = 4 waves.
// NO X-gather / no Xs LDS: stage-1 A-fragments load DIRECTLY from global xb
// (16B per lane, same bytes as the old gather+LDS round-trip, one fewer
// barrier, shorter critical path -- active occupancy is ~1 block/CU so
// serial phases are fully exposed). Pad rows clamp to token 0; epilogue
// masks them. Hs-only LDS (33 KB). Depth-1 prefetch on A and B.
// ---------------------------------------------------------------------------
__global__ __launch_bounds__(256, 3) void moe_expert_mfma(
    const ushort_t* __restrict__ xb,
    const ushort_t* __restrict__ W1f, const float* __restrict__ b1,
    const ushort_t* __restrict__ W2f, const float* __restrict__ b2,
    const int* __restrict__ gcounts, const int* __restrict__ lists,
    const float* __restrict__ wts, ushort_t* __restrict__ ybuf)
{
    const int e = blockIdx.x;
    const int half = blockIdx.y;

    __shared__ ushort_t Hs[TM * XS_LD];   // 33 KB
    __shared__ int cum[257];
    __shared__ int wsums[4];
    __shared__ int   toks[TM];
    __shared__ float wt_s[TM];

    const int tid = threadIdx.x;
    const int lane = tid & 63;
    const int w = tid >> 6;
    const int l15 = lane & 15;
    const int quad = lane >> 4;

    // block-wide exclusive prefix over the 256 gate segments of expert e
    {
        int v = gcounts[tid * NUM_EXPERTS + e];
#pragma unroll
        for (int s = 1; s < 64; s <<= 1) {
            int u = __shfl_up(v, s);
            if (lane >= s) v += u;
        }
        if (lane == 63) wsums[w] = v;
        __syncthreads();
        int off = 0;
        for (int i = 0; i < w; ++i) off += wsums[i];
        cum[tid + 1] = v + off;
        if (tid == 0) cum[0] = 0;
        __syncthreads();
    }
    const int n = cum[256];
    const int base = blockIdx.z * TM;
    if (base >= n) return;
    const int m = min(TM, n - base);

    if (tid < TM) {
        int p = base + tid;
        int tk = -1; float wv = 0.f;
        if (p < n) {
            int lo = 0;
#pragma unroll
            for (int s = 128; s >= 1; s >>= 1)
                if (cum[lo + s] <= p) lo += s;
            int idx = e * T_TOKENS + lo * 16 + (p - cum[lo]);
            tk = lists[idx]; wv = wts[idx];
        }
        toks[tid] = tk; wt_s[tid] = wv;
    }
    __syncthreads();

    // per-thread A row bases (clamp pad rows to token 0; masked in epilogue)
    const ushort_t* arow[4];
#pragma unroll
    for (int mt = 0; mt < 4; ++mt) {
        int tk = toks[mt * 16 + l15];
        arow[mt] = xb + (size_t)(tk < 0 ? 0 : tk) * D_MODEL + quad * 8;
    }

    // ---------------- stage 1: H = relu(X @ W1[:, half] + b1) --------------
    const ushort_t* W1p = W1f + (size_t)(e * 32 + half * 16 + w * 4) * 4096 + lane * 8;
    float b1v[4];
#pragma unroll
    for (int nt = 0; nt < 4; ++nt)
        b1v[nt] = b1[e * EXPERT_DIM + half * 256 + w * 64 + nt * 16 + l15];

    f32x4 acc1[4][4] = {};
    short8_t bc[4], ac[4];
#pragma unroll
    for (int nt = 0; nt < 4; ++nt) bc[nt] = *(const short8_t*)(W1p + nt * 4096);
#pragma unroll
    for (int mt = 0; mt < 4; ++mt) ac[mt] = *(const short8_t*)(arow[mt]);

    for (int ks = 0; ks < 8; ++ks) {
        short8_t bn[4], an[4];
        if (ks < 7) {
#pragma unroll
            for (int nt = 0; nt < 4; ++nt)
                bn[nt] = *(const short8_t*)(W1p + nt * 4096 + (ks + 1) * 512);
#pragma unroll
            for (int mt = 0; mt < 4; ++mt)
                an[mt] = *(const short8_t*)(arow[mt] + (ks + 1) * 32);
        }
#pragma unroll
        for (int mt = 0; mt < 4; ++mt)
#pragma unroll
            for (int nt = 0; nt < 4; ++nt)
                acc1[mt][nt] = __builtin_amdgcn_mfma_f32_16x16x32_bf16(
                    ac[mt], bc[nt], acc1[mt][nt], 0, 0, 0);
        if (ks < 7) {
#pragma unroll
            for (int nt = 0; nt < 4; ++nt) bc[nt] = bn[nt];
#pragma unroll
            for (int mt = 0; mt < 4; ++mt) ac[mt] = an[mt];
        }
    }

    // stage-2 B first frags + b2 prefetch before the barrier
    const ushort_t* W2p = W2f + (size_t)((e * 2 + half) * 16 + w * 4) * 4096 + lane * 8;
    short8_t bc2[4];
#pragma unroll
    for (int nt = 0; nt < 4; ++nt) bc2[nt] = *(const short8_t*)(W2p + nt * 4096);
    float b2v[4];
#pragma unroll
    for (int nt = 0; nt < 4; ++nt)
        b2v[nt] = half ? b2[e * D_MODEL + w * 64 + nt * 16 + l15] : 0.f;

    // relu + bias -> Hs (bf16, 256 cols of this half)
#pragma unroll
    for (int mt = 0; mt < 4; ++mt)
#pragma unroll
        for (int nt = 0; nt < 4; ++nt)
#pragma unroll
            for (int r = 0; r < 4; ++r) {
                int row = mt * 16 + quad * 4 + r;
                int col = w * 64 + nt * 16 + l15;
                float h = fmaxf(acc1[mt][nt][r] + b1v[nt], 0.f);
                Hs[row * XS_LD + col] = f2bf(h);
            }
    __syncthreads();

    // ---------------- stage 2: Y = H @ W2[half rows, :] --------------------
    f32x4 acc2[4][4] = {};
    for (int ks = 0; ks < 8; ++ks) {
        short8_t bn2[4];
        if (ks < 7) {
#pragma unroll
            for (int nt = 0; nt < 4; ++nt)
                bn2[nt] = *(const short8_t*)(W2p + nt * 4096 + (ks + 1) * 512);
        }
        short8_t a[4];
#pragma unroll
        for (int mt = 0; mt < 4; ++mt)
            a[mt] = *(const short8_t*)(Hs + (mt * 16 + l15) * XS_LD + ks * 32 + quad * 8);
#pragma unroll
        for (int mt = 0; mt < 4; ++mt)
#pragma unroll
            for (int nt = 0; nt < 4; ++nt)
                acc2[mt][nt] = __builtin_amdgcn_mfma_f32_16x16x32_bf16(
                    a[mt], bc2[nt], acc2[mt][nt], 0, 0, 0);
        if (ks < 7) {
#pragma unroll
            for (int nt = 0; nt < 4; ++nt) bc2[nt] = bn2[nt];
        }
    }

    // epilogue: bf16 stores into ybuf row (half*8+e)*4096 + p  (no atomics)
    ushort_t* yrow = ybuf + ((size_t)(half * NUM_EXPERTS + e) * T_TOKENS + base) * D_MODEL;
#pragma unroll
    for (int mt = 0; mt < 4; ++mt)
#pragma unroll
        for (int nt = 0; nt < 4; ++nt)
#pragma unroll
            for (int r = 0; r < 4; ++r) {
                int row = mt * 16 + quad * 4 + r;
                if (row < m) {
                    int col = w * 64 + nt * 16 + l15;
                    yrow[(size_t)row * D_MODEL + col] =
                        f2bf(wt_s[row] * (acc2[mt][nt][r] + b2v[nt]));
                }
            }
}

// ---------------------------------------------------------------------------
// Combine: out[t] = sum of 4 bf16 ybuf rows (2 experts x 2 halves).
// 256 blocks x 64 tokens (scan amortized 4x vs r8's 1024 blocks).
// ---------------------------------------------------------------------------
__global__ __launch_bounds__(256) void combine_kernel(
    const int* __restrict__ slots, const int* __restrict__ gcounts,
    const ushort_t* __restrict__ ybuf, float* __restrict__ out)
{
    __shared__ int cum8[NUM_EXPERTS][257];
    const int tid = threadIdx.x;
    const int lane = tid & 63;
    const int wv = tid >> 6;
#pragma unroll
    for (int rpt = 0; rpt < 2; ++rpt) {
        int e = wv + rpt * 4;
        int carry = 0;
        for (int ch = 0; ch < 4; ++ch) {
            int v = gcounts[(ch * 64 + lane) * NUM_EXPERTS + e];
#pragma unroll
            for (int s = 1; s < 64; s <<= 1) {
                int u = __shfl_up(v, s);
                if (lane >= s) v += u;
            }
            v += carry;
            cum8[e][ch * 64 + lane + 1] = v;
            carry = __shfl(v, 63);
        }
        if (lane == 0) cum8[e][0] = 0;
    }
    __syncthreads();

    const size_t H = (size_t)NUM_EXPERTS * T_TOKENS * D_MODEL;  // half stride
#pragma unroll
    for (int it = 0; it < 16; ++it) {
        int t = blockIdx.x * 64 + wv * 16 + it;
        int sl = slots[t];
        int s0 = sl & 0xFFFF, s1 = (sl >> 16) & 0xFFFF;
        int e0 = (s0 >> 12) & 7, g0 = (s0 >> 4) & 255, lp0 = s0 & 15;
        int e1 = (s1 >> 12) & 7, g1 = (s1 >> 4) & 255, lp1 = s1 & 15;
        int p0 = cum8[e0][g0] + lp0;
        int p1 = cum8[e1][g1] + lp1;
        size_t o0 = ((size_t)e0 * T_TOKENS + p0) * D_MODEL + lane * 4;
        size_t o1 = ((size_t)e1 * T_TOKENS + p1) * D_MODEL + lane * 4;
        ushort4 a = *(const ushort4*)(ybuf + o0);
        ushort4 b = *(const ushort4*)(ybuf + o0 + H);
        ushort4 c = *(const ushort4*)(ybuf + o1);
        ushort4 d = *(const ushort4*)(ybuf + o1 + H);
        float4 r;
        r.x = bf2f(a.x) + bf2f(b.x) + bf2f(c.x) + bf2f(d.x);
        r.y = bf2f(a.y) + bf2f(b.y) + bf2f(c.y) + bf2f(d.y);
        r.z = bf2f(a.z) + bf2f(b.z) + bf2f(c.z) + bf2f(d.z);
        r.w = bf2f(a.w) + bf2f(b.w) + bf2f(c.w) + bf2f(d.w);
        *(float4*)(out + (size_t)t * D_MODEL + lane * 4) = r;
    }
}

extern "C" void kernel_launch(void* const* d_in, const int* in_sizes, int n_in,
                              void* d_out, int out_size, void* d_ws, size_t ws_size,
                              hipStream_t stream)
{
    const float* x    = (const float*)d_in[0];
    const float* Wg   = (const float*)d_in[1];
    const float* bg   = (const float*)d_in[2];
    const float* bias = (const float*)d_in[3];
    const float* W1   = (const float*)d_in[4];
    const float* b1   = (const float*)d_in[5];
    const float* W2   = (const float*)d_in[6];
    const float* b2   = (const float*)d_in[7];
    float* out = (float*)d_out;

    // workspace layout (~40 MB of the 256 MB ws)
    char* ws = (char*)d_ws;
    int*      gcounts = (int*)ws;                        // 8 KB (2048 ints)
    int*      lists   = (int*)(ws + 8192);               // 128 KB
    float*    wts     = (float*)(ws + 139264);           // 128 KB
    int*      slots   = (int*)(ws + 270336);             // 16 KB
    ushort_t* xb      = (ushort_t*)(ws + 524288);        // 2 MB
    ushort_t* W1f     = (ushort_t*)(ws + 2621440);       // 2 MB
    ushort_t* W2f     = (ushort_t*)(ws + 4718592);       // 2 MB
    ushort_t* ybuf    = (ushort_t*)(ws + 6815744);       // 33.5 MB (bf16)

    prep_kernel<<<NGB + 1024, 256, 0, stream>>>(
        x, Wg, bg, bias, W1, W2, W1f, W2f, xb, gcounts, lists, wts, slots);

    moe_expert_mfma<<<dim3(NUM_EXPERTS, 2, T_TOKENS / TM), 256, 0, stream>>>(
        xb, W1f, b1, W2f, b2, gcounts, lists, wts, ybuf);

    combine_kernel<<<T_TOKENS / 64, 256, 0, stream>>>(slots, gcounts, ybuf, out);
}

// Round 10
// 104.866 us; speedup vs baseline: 1.0302x; 1.0302x over previous
//
#include <hip/hip_runtime.h>
#include <hip/hip_bf16.h>
#include <math.h>

#define D_MODEL 256
#define EXPERT_DIM 512
#define NUM_EXPERTS 8
#define T_TOKENS 4096
#define TM 64
#define NGB 256      // gate blocks (16 tokens each)
#define XS_LD 264    // 256+8 bf16 pad: 528B row (measured 0 conflicts)

typedef unsigned short ushort_t;
typedef short short8_t __attribute__((ext_vector_type(8)));
typedef float f32x4 __attribute__((ext_vector_type(4)));

__device__ __forceinline__ ushort_t f2bf(float f) {
    unsigned int u = __float_as_uint(f);
    u += 0x7FFFu + ((u >> 16) & 1u);   // round-to-nearest-even
    return (ushort_t)(u >> 16);
}
__device__ __forceinline__ float bf2f(ushort_t u) {
    return __uint_as_float((unsigned int)u << 16);
}

// ---------------------------------------------------------------------------
// Fused prep (identical to r8).
// Blocks 0..255: gate, 16 tokens/block, 16 threads/token, register x,
//   16-lane shuffle reduce, LDS-atomic compaction into per-(seg,expert)
//   width-16 segments; plain-store counts; emits bf16 xb.
// Blocks 256..1279: weight convert fp32 -> bf16 MFMA-fragment order.
// W1f: idx = e<<14 | ntile(5b)<<9 | ks(3b)<<6 | lane   (8 bf16 elems each)
// W2f: idx = e<<14 | half<<13 | ntile(4b)<<9 | ks(3b)<<6 | lane
// ---------------------------------------------------------------------------
__global__ __launch_bounds__(256) void prep_kernel(
    const float* __restrict__ x, const float* __restrict__ Wg,
    const float* __restrict__ bg, const float* __restrict__ bias,
    const float* __restrict__ W1, const float* __restrict__ W2,
    ushort_t* __restrict__ W1f, ushort_t* __restrict__ W2f,
    ushort_t* __restrict__ xb,
    int* __restrict__ gcounts, int* __restrict__ lists,
    float* __restrict__ wts, int* __restrict__ slots)
{
    __shared__ int lcount[NUM_EXPERTS];
    const int tid = threadIdx.x;

    if (blockIdx.x < NGB) {
        // ---------------- gate role ----------------
        const int gb = blockIdx.x;
        const int r = tid >> 4;        // token 0..15
        const int c = tid & 15;        // k-chunk 0..15 (16 k each)
        const int t = gb * 16 + r;
        if (tid < NUM_EXPERTS) lcount[tid] = 0;

        float xr[16];
        const float4* xp = (const float4*)(x + (size_t)t * D_MODEL + c * 16);
#pragma unroll
        for (int q = 0; q < 4; ++q) {
            float4 v = xp[q];
            xr[q * 4 + 0] = v.x; xr[q * 4 + 1] = v.y;
            xr[q * 4 + 2] = v.z; xr[q * 4 + 3] = v.w;
        }
        ushort_t o16[16];
#pragma unroll
        for (int j = 0; j < 16; ++j) o16[j] = f2bf(xr[j]);
        ushort_t* xbp = xb + (size_t)t * D_MODEL + c * 16;
        *(int4*)(xbp)     = *(int4*)(o16);
        *(int4*)(xbp + 8) = *(int4*)(o16 + 8);

        float acc[NUM_EXPERTS];
#pragma unroll
        for (int e = 0; e < NUM_EXPERTS; ++e) acc[e] = 0.f;
#pragma unroll
        for (int j = 0; j < 16; ++j) {
            const float4* wg = (const float4*)(Wg + (c * 16 + j) * NUM_EXPERTS);
            float4 w0 = wg[0], w1 = wg[1];
            float xv = xr[j];
            acc[0] += xv * w0.x; acc[1] += xv * w0.y;
            acc[2] += xv * w0.z; acc[3] += xv * w0.w;
            acc[4] += xv * w1.x; acc[5] += xv * w1.y;
            acc[6] += xv * w1.z; acc[7] += xv * w1.w;
        }
#pragma unroll
        for (int e = 0; e < NUM_EXPERTS; ++e) {
#pragma unroll
            for (int s = 1; s < 16; s <<= 1) acc[e] += __shfl_xor(acc[e], s);
        }
        __syncthreads();
        if (c == 0) {
            float v0 = -3.0e38f, v1 = -3.0e38f; int i0 = 0, i1 = 0;
#pragma unroll
            for (int e = 0; e < NUM_EXPERTS; ++e) {
                float v = acc[e] + bg[e] + bias[e];
                if (v > v0) { v1 = v0; i1 = i0; v0 = v; i0 = e; }
                else if (v > v1) { v1 = v; i1 = e; }
            }
            float e1 = __expf(v1 - v0);
            float inv = 1.f / (1.f + e1);
            float w0 = inv, w1 = e1 * inv;

            int p0 = atomicAdd(&lcount[i0], 1);    // LDS atomics only
            int p1 = atomicAdd(&lcount[i1], 1);
            lists[i0 * T_TOKENS + gb * 16 + p0] = t;
            wts  [i0 * T_TOKENS + gb * 16 + p0] = w0;
            lists[i1 * T_TOKENS + gb * 16 + p1] = t;
            wts  [i1 * T_TOKENS + gb * 16 + p1] = w1;
            slots[t] = (i0 << 12 | gb << 4 | p0) | ((i1 << 12 | gb << 4 | p1) << 16);
        }
        __syncthreads();
        if (tid < NUM_EXPERTS) gcounts[gb * NUM_EXPERTS + tid] = lcount[tid];
    } else {
        // ---------------- convert role ----------------
        int gid = (blockIdx.x - NGB) * 256 + tid;    // 0 .. 262143
        bool isW2 = gid >= 131072;
        int idx = isW2 ? gid - 131072 : gid;
        int lane = idx & 63;
        int l15 = lane & 15, quad = lane >> 4;
        int ks = (idx >> 6) & 7;
        ushort_t o[8];
        if (!isW2) {
            int ntile = (idx >> 9) & 31, e = idx >> 14;
            int nn = ntile * 16 + l15;
            int k0 = ks * 32 + quad * 8;
            const float* s = W1 + ((size_t)e * D_MODEL + k0) * EXPERT_DIM + nn;
#pragma unroll
            for (int j = 0; j < 8; ++j) o[j] = f2bf(s[j * EXPERT_DIM]);
            *(int4*)(W1f + (size_t)idx * 8) = *(int4*)o;
        } else {
            int ntile = (idx >> 9) & 15, half = (idx >> 13) & 1, e = idx >> 14;
            int nn = ntile * 16 + l15;
            int k0 = half * 256 + ks * 32 + quad * 8;
            const float* s = W2 + ((size_t)e * EXPERT_DIM + k0) * D_MODEL + nn;
#pragma unroll
            for (int j = 0; j < 8; ++j) o[j] = f2bf(s[j * D_MODEL]);
            *(int4*)(W2f + (size_t)idx * 8) = *(int4*)o;
        }
    }
}

// ---------------------------------------------------------------------------
// Expert FFN, bf16 MFMA (r8 structure: LDS X-gather restored — r9's direct
// global A-loads were uncoalesced 16B/lane scatter, -3.4us). grid (expert,
// half, tile64), block 256 = 4 waves. Stage-1 B prefetch issued FIRST
// (depends only on blockIdx) so the weight fetch overlaps the scan phase.
// Xs/Hs alias one 33 KB LDS buffer; depth-1 B prefetch in both K-loops;
// bf16 plain stores to ybuf.
// ---------------------------------------------------------------------------
__global__ __launch_bounds__(256, 3) void moe_expert_mfma(
    const ushort_t* __restrict__ xb,
    const ushort_t* __restrict__ W1f, const float* __restrict__ b1,
    const ushort_t* __restrict__ W2f, const float* __restrict__ b2,
    const int* __restrict__ gcounts, const int* __restrict__ lists,
    const float* __restrict__ wts, ushort_t* __restrict__ ybuf)
{
    const int e = blockIdx.x;
    const int half = blockIdx.y;

    __shared__ ushort_t XH[TM * XS_LD];   // 33 KB: Xs, then reused as Hs
    __shared__ int cum[257];
    __shared__ int wsums[4];
    __shared__ int   toks[TM];
    __shared__ float wt_s[TM];

    const int tid = threadIdx.x;
    const int lane = tid & 63;
    const int w = tid >> 6;
    const int l15 = lane & 15;
    const int quad = lane >> 4;

    // stage-1 B prefetch issued before anything else (hides L2 latency
    // behind the scan + toks phases)
    const ushort_t* W1p = W1f + (size_t)(e * 32 + half * 16 + w * 4) * 4096 + lane * 8;
    short8_t bc[4];
#pragma unroll
    for (int nt = 0; nt < 4; ++nt) bc[nt] = *(const short8_t*)(W1p + nt * 4096);

    // block-wide exclusive prefix over the 256 gate segments of expert e
    {
        int v = gcounts[tid * NUM_EXPERTS + e];
#pragma unroll
        for (int s = 1; s < 64; s <<= 1) {
            int u = __shfl_up(v, s);
            if (lane >= s) v += u;
        }
        if (lane == 63) wsums[w] = v;
        __syncthreads();
        int off = 0;
        for (int i = 0; i < w; ++i) off += wsums[i];
        cum[tid + 1] = v + off;
        if (tid == 0) cum[0] = 0;
        __syncthreads();
    }
    const int n = cum[256];
    const int base = blockIdx.z * TM;
    if (base >= n) return;
    const int m = min(TM, n - base);

    if (tid < TM) {
        int p = base + tid;
        int tk = -1; float wv = 0.f;
        if (p < n) {
            int lo = 0;
#pragma unroll
            for (int s = 128; s >= 1; s >>= 1)
                if (cum[lo + s] <= p) lo += s;
            int idx = e * T_TOKENS + lo * 16 + (p - cum[lo]);
            tk = lists[idx]; wv = wts[idx];
        }
        toks[tid] = tk; wt_s[tid] = wv;
    }
    __syncthreads();

    // gather X tile from bf16 xb: 512B per token row, coalesced
    for (int c = tid; c < TM * 32; c += 256) {
        int r = c >> 5, c8 = c & 31;
        int tk = toks[r];
        int4 v = make_int4(0, 0, 0, 0);
        if (tk >= 0) v = *(const int4*)(xb + (size_t)tk * D_MODEL + c8 * 8);
        *(int4*)(XH + r * XS_LD + c8 * 8) = v;
    }
    __syncthreads();

    // ---------------- stage 1: H = relu(X @ W1[:, half] + b1) --------------
    float b1v[4];
#pragma unroll
    for (int nt = 0; nt < 4; ++nt)
        b1v[nt] = b1[e * EXPERT_DIM + half * 256 + w * 64 + nt * 16 + l15];

    f32x4 acc1[4][4] = {};
    for (int ks = 0; ks < 8; ++ks) {
        short8_t bn[4];
        if (ks < 7) {
#pragma unroll
            for (int nt = 0; nt < 4; ++nt)
                bn[nt] = *(const short8_t*)(W1p + nt * 4096 + (ks + 1) * 512);
        }
        short8_t a[4];
#pragma unroll
        for (int mt = 0; mt < 4; ++mt)
            a[mt] = *(const short8_t*)(XH + (mt * 16 + l15) * XS_LD + ks * 32 + quad * 8);
#pragma unroll
        for (int mt = 0; mt < 4; ++mt)
#pragma unroll
            for (int nt = 0; nt < 4; ++nt)
                acc1[mt][nt] = __builtin_amdgcn_mfma_f32_16x16x32_bf16(
                    a[mt], bc[nt], acc1[mt][nt], 0, 0, 0);
        if (ks < 7) {
#pragma unroll
            for (int nt = 0; nt < 4; ++nt) bc[nt] = bn[nt];
        }
    }

    // stage-2 B first frags + b2 prefetch before the barrier
    const ushort_t* W2p = W2f + (size_t)((e * 2 + half) * 16 + w * 4) * 4096 + lane * 8;
    short8_t bc2[4];
#pragma unroll
    for (int nt = 0; nt < 4; ++nt) bc2[nt] = *(const short8_t*)(W2p + nt * 4096);
    float b2v[4];
#pragma unroll
    for (int nt = 0; nt < 4; ++nt)
        b2v[nt] = half ? b2[e * D_MODEL + w * 64 + nt * 16 + l15] : 0.f;

    __syncthreads();   // all stage-1 X reads done; XH becomes Hs
#pragma unroll
    for (int mt = 0; mt < 4; ++mt)
#pragma unroll
        for (int nt = 0; nt < 4; ++nt)
#pragma unroll
            for (int r = 0; r < 4; ++r) {
                int row = mt * 16 + quad * 4 + r;
                int col = w * 64 + nt * 16 + l15;
                float h = fmaxf(acc1[mt][nt][r] + b1v[nt], 0.f);
                XH[row * XS_LD + col] = f2bf(h);
            }
    __syncthreads();

    // ---------------- stage 2: Y = H @ W2[half rows, :] --------------------
    f32x4 acc2[4][4] = {};
    for (int ks = 0; ks < 8; ++ks) {
        short8_t bn2[4];
        if (ks < 7) {
#pragma unroll
            for (int nt = 0; nt < 4; ++nt)
                bn2[nt] = *(const short8_t*)(W2p + nt * 4096 + (ks + 1) * 512);
        }
        short8_t a[4];
#pragma unroll
        for (int mt = 0; mt < 4; ++mt)
            a[mt] = *(const short8_t*)(XH + (mt * 16 + l15) * XS_LD + ks * 32 + quad * 8);
#pragma unroll
        for (int mt = 0; mt < 4; ++mt)
#pragma unroll
            for (int nt = 0; nt < 4; ++nt)
                acc2[mt][nt] = __builtin_amdgcn_mfma_f32_16x16x32_bf16(
                    a[mt], bc2[nt], acc2[mt][nt], 0, 0, 0);
        if (ks < 7) {
#pragma unroll
            for (int nt = 0; nt < 4; ++nt) bc2[nt] = bn2[nt];
        }
    }

    // epilogue: bf16 stores into ybuf row (half*8+e)*4096 + p  (no atomics)
    ushort_t* yrow = ybuf + ((size_t)(half * NUM_EXPERTS + e) * T_TOKENS + base) * D_MODEL;
#pragma unroll
    for (int mt = 0; mt < 4; ++mt)
#pragma unroll
        for (int nt = 0; nt < 4; ++nt)
#pragma unroll
            for (int r = 0; r < 4; ++r) {
                int row = mt * 16 + quad * 4 + r;
                if (row < m) {
                    int col = w * 64 + nt * 16 + l15;
                    yrow[(size_t)row * D_MODEL + col] =
                        f2bf(wt_s[row] * (acc2[mt][nt][r] + b2v[nt]));
                }
            }
}

// ---------------------------------------------------------------------------
// Combine: out[t] = sum of 4 bf16 ybuf rows (2 experts x 2 halves).
// 256 blocks x 64 tokens (scan amortized 4x).
// ---------------------------------------------------------------------------
__global__ __launch_bounds__(256) void combine_kernel(
    const int* __restrict__ slots, const int* __restrict__ gcounts,
    const ushort_t* __restrict__ ybuf, float* __restrict__ out)
{
    __shared__ int cum8[NUM_EXPERTS][257];
    const int tid = threadIdx.x;
    const int lane = tid & 63;
    const int wv = tid >> 6;
#pragma unroll
    for (int rpt = 0; rpt < 2; ++rpt) {
        int e = wv + rpt * 4;
        int carry = 0;
        for (int ch = 0; ch < 4; ++ch) {
            int v = gcounts[(ch * 64 + lane) * NUM_EXPERTS + e];
#pragma unroll
            for (int s = 1; s < 64; s <<= 1) {
                int u = __shfl_up(v, s);
                if (lane >= s) v += u;
            }
            v += carry;
            cum8[e][ch * 64 + lane + 1] = v;
            carry = __shfl(v, 63);
        }
        if (lane == 0) cum8[e][0] = 0;
    }
    __syncthreads();

    const size_t H = (size_t)NUM_EXPERTS * T_TOKENS * D_MODEL;  // half stride
#pragma unroll
    for (int it = 0; it < 16; ++it) {
        int t = blockIdx.x * 64 + wv * 16 + it;
        int sl = slots[t];
        int s0 = sl & 0xFFFF, s1 = (sl >> 16) & 0xFFFF;
        int e0 = (s0 >> 12) & 7, g0 = (s0 >> 4) & 255, lp0 = s0 & 15;
        int e1 = (s1 >> 12) & 7, g1 = (s1 >> 4) & 255, lp1 = s1 & 15;
        int p0 = cum8[e0][g0] + lp0;
        int p1 = cum8[e1][g1] + lp1;
        size_t o0 = ((size_t)e0 * T_TOKENS + p0) * D_MODEL + lane * 4;
        size_t o1 = ((size_t)e1 * T_TOKENS + p1) * D_MODEL + lane * 4;
        ushort4 a = *(const ushort4*)(ybuf + o0);
        ushort4 b = *(const ushort4*)(ybuf + o0 + H);
        ushort4 c = *(const ushort4*)(ybuf + o1);
        ushort4 d = *(const ushort4*)(ybuf + o1 + H);
        float4 r;
        r.x = bf2f(a.x) + bf2f(b.x) + bf2f(c.x) + bf2f(d.x);
        r.y = bf2f(a.y) + bf2f(b.y) + bf2f(c.y) + bf2f(d.y);
        r.z = bf2f(a.z) + bf2f(b.z) + bf2f(c.z) + bf2f(d.z);
        r.w = bf2f(a.w) + bf2f(b.w) + bf2f(c.w) + bf2f(d.w);
        *(float4*)(out + (size_t)t * D_MODEL + lane * 4) = r;
    }
}

extern "C" void kernel_launch(void* const* d_in, const int* in_sizes, int n_in,
                              void* d_out, int out_size, void* d_ws, size_t ws_size,
                              hipStream_t stream)
{
    const float* x    = (const float*)d_in[0];
    const float* Wg   = (const float*)d_in[1];
    const float* bg   = (const float*)d_in[2];
    const float* bias = (const float*)d_in[3];
    const float* W1   = (const float*)d_in[4];
    const float* b1   = (const float*)d_in[5];
    const float* W2   = (const float*)d_in[6];
    const float* b2   = (const float*)d_in[7];
    float* out = (float*)d_out;

    // workspace layout (~40 MB of the 256 MB ws)
    char* ws = (char*)d_ws;
    int*      gcounts = (int*)ws;                        // 8 KB (2048 ints)
    int*      lists   = (int*)(ws + 8192);               // 128 KB
    float*    wts     = (float*)(ws + 139264);           // 128 KB
    int*      slots   = (int*)(ws + 270336);             // 16 KB
    ushort_t* xb      = (ushort_t*)(ws + 524288);        // 2 MB
    ushort_t* W1f     = (ushort_t*)(ws + 2621440);       // 2 MB
    ushort_t* W2f     = (ushort_t*)(ws + 4718592);       // 2 MB
    ushort_t* ybuf    = (ushort_t*)(ws + 6815744);       // 33.5 MB (bf16)

    prep_kernel<<<NGB + 1024, 256, 0, stream>>>(
        x, Wg, bg, bias, W1, W2, W1f, W2f, xb, gcounts, lists, wts, slots);

    moe_expert_mfma<<<dim3(NUM_EXPERTS, 2, T_TOKENS / TM), 256, 0, stream>>>(
        xb, W1f, b1, W2f, b2, gcounts, lists, wts, ybuf);

    combine_kernel<<<T_TOKENS / 64, 256, 0, stream>>>(slots, gcounts, ybuf, out);
}